// Round 1
// baseline (564.002 us; speedup 1.0000x reference)
//
#include <hip/hip_runtime.h>
#include <hip/hip_bf16.h>

// Fused hyperbolic MLP forward.
// Math note: logmap0(proj(expmap0(u))) == u * min(1, A/||u||), A = atanh(0.999).
// So the whole pipeline is 3 GEMMs with per-row clip-norm/tanh between them,
// plus a 16-dim mobius epilogue (general in bc; collapses for bc=0).

typedef __bf16 bfrag __attribute__((ext_vector_type(8)));   // MFMA A/B operand (4 VGPR)
typedef __bf16 bf4   __attribute__((ext_vector_type(4)));
typedef float  ffrag __attribute__((ext_vector_type(4)));   // MFMA C/D (4 VGPR)

#define ACLIP 3.8002012f   // atanh(0.999)

__device__ __forceinline__ float rsum16(float v) {
  v += __shfl_xor(v, 1);
  v += __shfl_xor(v, 2);
  v += __shfl_xor(v, 4);
  v += __shfl_xor(v, 8);
  return v;
}
__device__ __forceinline__ float rsum64(float v) {
  v = rsum16(v);
  v += __shfl_xor(v, 16);
  v += __shfl_xor(v, 32);
  return v;
}
__device__ __forceinline__ float tanh_fast(float x) {
  float ax = fabsf(x);
  float e = __expf(fminf(2.0f * ax, 30.0f));
  float t = 1.0f - __fdividef(2.0f, e + 1.0f);
  return copysignf(t, x);
}

// ---------------------------------------------------------------------------
// prep: reorder W1/W2/Wc (f32 row-major [out][in]) into bf16 MFMA b-fragment
// order in ws:  slot(stage, ks, nt, lane) holds W[nt*16 + (lane&15)]
//                                              [ks*32 + (lane>>4)*8 .. +7]
// layout: per stage, slot = ks*(NT*64) + nt*64 + lane  (16B per slot)
// W1 at elem 0, W2 at 65536, Wc at 131072 (total 135168 bf16 = 264 KiB)
// ---------------------------------------------------------------------------
__global__ void prep_kernel(const float* __restrict__ W1, const float* __restrict__ W2,
                            const float* __restrict__ Wc, __bf16* __restrict__ wsb) {
  int g = blockIdx.x * 256 + threadIdx.x;   // 0..16895
  const float* src; int s, base;
  if (g < 8192)        { src = W1; s = g;         base = 0;      }
  else if (g < 16384)  { src = W2; s = g - 8192;  base = 65536;  }
  else                 { src = Wc; s = g - 16384; base = 131072; }
  int l = s & 63, t = s >> 6;
  int nt, ks;
  if (g < 16384) { nt = t & 15; ks = t >> 4; }   // slot = ks*1024 + nt*64 + l
  else           { nt = 0;      ks = t;      }   // slot = ks*64 + l
  int row  = nt * 16 + (l & 15);
  int col0 = ks * 32 + (l >> 4) * 8;
  bfrag v;
  #pragma unroll
  for (int j = 0; j < 8; ++j) v[j] = (__bf16)src[row * 256 + col0 + j];
  *(bfrag*)(wsb + base + s * 8) = v;
}

// ---------------------------------------------------------------------------
// fused main kernel: 64 rows per block, 4 waves, each wave owns a 64-col slice
// (4x4 grid of 16x16 MFMA tiles). A-tile in LDS with XOR swizzle
// (phys_colbyte = logical ^ ((row&7)<<4)) -> conflict-free ds_read_b128.
// ---------------------------------------------------------------------------
__global__ __launch_bounds__(256) void fused_kernel(
    const float* __restrict__ x, const float* __restrict__ b1,
    const float* __restrict__ b2, const float* __restrict__ bc,
    const __bf16* __restrict__ wsb, float* __restrict__ out) {
  __shared__ __bf16 At[64 * 256];   // 32 KiB, swizzled row-major, 512 B/row
  __shared__ __bf16 Bt[1024 * 8];   // 16 KiB, one k-step of B fragments
  __shared__ float nrmA[64][4];
  __shared__ float nrmB[64][4];

  const int tid  = threadIdx.x;
  const int w    = tid >> 6;
  const int lane = tid & 63;
  const int lrow = lane & 15;
  const int lgrp = lane >> 4;
  const int swzA = (lrow & 7) << 4;
  const long long rowg = (long long)blockIdx.x * 64;

  // ---- stage 0: load x (16 rows per wave), clip_norm(x, A), write bf16 A ----
  #pragma unroll
  for (int rr = 0; rr < 16; ++rr) {
    int row = w * 16 + rr;
    const float4 v = *(const float4*)(x + (rowg + row) * 256 + lane * 4);
    float ss = rsum64(v.x * v.x + v.y * v.y + v.z * v.z + v.w * v.w);
    float f = fminf(1.0f, ACLIP * rsqrtf(fmaxf(ss, 1e-30f)));
    bf4 z;
    z[0] = (__bf16)(v.x * f); z[1] = (__bf16)(v.y * f);
    z[2] = (__bf16)(v.z * f); z[3] = (__bf16)(v.w * f);
    *(bf4*)((char*)At + row * 512 + ((lane * 8) ^ ((row & 7) << 4))) = z;
  }

  ffrag acc[4][4];

  #pragma unroll
  for (int st = 0; st < 2; ++st) {
    const __bf16* wb   = wsb + (st ? 65536 : 0);
    const float*  bias = st ? b2 : b1;
    #pragma unroll
    for (int rt = 0; rt < 4; ++rt)
      #pragma unroll
      for (int ct = 0; ct < 4; ++ct)
        acc[rt][ct] = (ffrag){0.f, 0.f, 0.f, 0.f};

    bfrag pre[4];
    #pragma unroll
    for (int i = 0; i < 4; ++i) pre[i] = *(const bfrag*)(wb + (i * 256 + tid) * 8);

    for (int ks = 0; ks < 8; ++ks) {
      __syncthreads();                       // prior k-step reads (and A writes) done
      #pragma unroll
      for (int i = 0; i < 4; ++i) *(bfrag*)(Bt + (i * 256 + tid) * 8) = pre[i];
      __syncthreads();                       // staged slice visible
      if (ks < 7) {
        #pragma unroll
        for (int i = 0; i < 4; ++i)
          pre[i] = *(const bfrag*)(wb + ((ks + 1) * 1024 + i * 256 + tid) * 8);
      }
      bfrag areg[4], breg[4];
      #pragma unroll
      for (int rt = 0; rt < 4; ++rt)
        areg[rt] = *(const bfrag*)((const char*)At + (rt * 16 + lrow) * 512 +
                                   ((ks * 64 + lgrp * 16) ^ swzA));
      #pragma unroll
      for (int ct = 0; ct < 4; ++ct)
        breg[ct] = *(const bfrag*)(Bt + ((w * 4 + ct) * 64 + lane) * 8);
      #pragma unroll
      for (int rt = 0; rt < 4; ++rt)
        #pragma unroll
        for (int ct = 0; ct < 4; ++ct)
          acc[rt][ct] = __builtin_amdgcn_mfma_f32_16x16x32_bf16(
              areg[rt], breg[ct], acc[rt][ct], 0, 0, 0);
    }
    __syncthreads();   // all GEMM A-reads done before elementwise A-writes

    // ---- elementwise: +bias, clip_norm(.,A), tanh, clip_norm(.,A) ----
    #pragma unroll
    for (int ct = 0; ct < 4; ++ct) {
      float bb = bias[w * 64 + ct * 16 + lrow];
      #pragma unroll
      for (int rt = 0; rt < 4; ++rt)
        #pragma unroll
        for (int r = 0; r < 4; ++r) acc[rt][ct][r] += bb;
    }
    #pragma unroll
    for (int rt = 0; rt < 4; ++rt)
      #pragma unroll
      for (int r = 0; r < 4; ++r) {
        float s = 0.f;
        #pragma unroll
        for (int ct = 0; ct < 4; ++ct) s += acc[rt][ct][r] * acc[rt][ct][r];
        s = rsum16(s);
        if (lrow == 0) nrmA[rt * 16 + lgrp * 4 + r][w] = s;
      }
    __syncthreads();
    #pragma unroll
    for (int rt = 0; rt < 4; ++rt)
      #pragma unroll
      for (int r = 0; r < 4; ++r) {
        const float4 nv = *(const float4*)&nrmA[rt * 16 + lgrp * 4 + r][0];
        float tot = nv.x + nv.y + nv.z + nv.w;
        float f = fminf(1.0f, ACLIP * rsqrtf(fmaxf(tot, 1e-30f)));
        float s2 = 0.f;
        #pragma unroll
        for (int ct = 0; ct < 4; ++ct) {
          float z = tanh_fast(acc[rt][ct][r] * f);
          acc[rt][ct][r] = z;
          s2 += z * z;
        }
        s2 = rsum16(s2);
        if (lrow == 0) nrmB[rt * 16 + lgrp * 4 + r][w] = s2;
      }
    __syncthreads();
    #pragma unroll
    for (int rt = 0; rt < 4; ++rt)
      #pragma unroll
      for (int r = 0; r < 4; ++r) {
        const float4 nv = *(const float4*)&nrmB[rt * 16 + lgrp * 4 + r][0];
        float tot = nv.x + nv.y + nv.z + nv.w;
        float f2 = fminf(1.0f, ACLIP * rsqrtf(fmaxf(tot, 1e-30f)));
        int row = rt * 16 + lgrp * 4 + r;
        #pragma unroll
        for (int ct = 0; ct < 4; ++ct) {
          float y = acc[rt][ct][r] * f2;
          int cb = (w * 64 + ct * 16 + lrow) * 2;
          *(__bf16*)((char*)At + row * 512 + (cb ^ ((row & 7) << 4))) = (__bf16)y;
        }
      }
  }
  __syncthreads();   // y2 visible for classifier a-reads

  // ---- classifier: m = y2 @ Wc^T (16 cols), then mobius epilogue ----
  float bcv = bc[lrow];
  float pb2 = rsum16(bcv * bcv);
  float nb  = sqrtf(fmaxf(pb2, 1e-30f));
  float tnb = tanh_fast(nb);
  float pratio = (nb < 1e-4f) ? 1.0f : __fdividef(fminf(tnb, 0.999f), nb);
  float pj = bcv * pratio;            // hyp_bias component (class lrow)
  float p2 = rsum16(pj * pj);

  ffrag c2 = (ffrag){0.f, 0.f, 0.f, 0.f};
  #pragma unroll
  for (int ks = 0; ks < 8; ++ks) {
    bfrag a = *(const bfrag*)((const char*)At + (w * 16 + lrow) * 512 +
                              ((ks * 64 + lgrp * 16) ^ swzA));
    bfrag b = *(const bfrag*)(wsb + 131072 + (ks * 64 + lane) * 8);
    c2 = __builtin_amdgcn_mfma_f32_16x16x32_bf16(a, b, c2, 0, 0, 0);
  }
  #pragma unroll
  for (int r = 0; r < 4; ++r) {
    float m  = c2[r];                    // m' element, class lrow
    float g2 = rsum16(m * m);
    float gn = sqrtf(fmaxf(g2, 1e-30f));
    float tg = tanh_fast(gn);
    float rn = fminf(tg, 0.999f);
    float ratio = (gn < 1e-4f) ? 1.0f : __fdividef(rn, gn);
    float xj = m * ratio;                // proj(mobius_matvec) component
    float x2 = ratio * ratio * g2;       // ||x||^2
    float xy = rsum16(xj * pj);
    float na = 1.f + 2.f * xy + p2;
    float de = fmaxf(1.f + 2.f * xy + x2 * p2, 1e-15f);
    float r2j = (na * xj + (1.f - x2) * pj) / de;   // mobius_add
    float n2s = rsum16(r2j * r2j);
    float n2  = sqrtf(fmaxf(n2s, 1e-30f));
    float pscl = (n2 > 0.999f) ? (0.999f / n2) : 1.0f;
    r2j *= pscl;
    float n3 = fminf(n2, 0.999f);
    float lfac = (n3 < 1e-4f)
                     ? 1.0f
                     : __fdividef(0.5f * __logf((1.f + n3) / (1.f - n3)), n3);
    float lg = r2j * lfac;               // logits
    float sp = (lg > 20.f) ? lg : log1pf(__expf(lg));
    long long row = rowg + w * 16 + lgrp * 4 + r;
    out[row * 16 + lrow] = sp;
  }
}

extern "C" void kernel_launch(void* const* d_in, const int* in_sizes, int n_in,
                              void* d_out, int out_size, void* d_ws, size_t ws_size,
                              hipStream_t stream) {
  (void)in_sizes; (void)n_in; (void)out_size; (void)ws_size;
  const float* x  = (const float*)d_in[0];
  const float* W1 = (const float*)d_in[1];
  const float* b1 = (const float*)d_in[2];
  const float* W2 = (const float*)d_in[3];
  const float* b2 = (const float*)d_in[4];
  const float* Wc = (const float*)d_in[5];
  const float* bc = (const float*)d_in[6];
  __bf16* wsb = (__bf16*)d_ws;          // needs 270336 B

  prep_kernel<<<66, 256, 0, stream>>>(W1, W2, Wc, wsb);
  fused_kernel<<<4096, 256, 0, stream>>>(x, b1, b2, bc, wsb, (float*)d_out);
}

// Round 2
// 428.300 us; speedup vs baseline: 1.3168x; 1.3168x over previous
//
#include <hip/hip_runtime.h>
#include <hip/hip_bf16.h>

// Fused hyperbolic MLP forward.
// Math note: logmap0(proj(expmap0(u))) == u * min(1, A/||u||), A = atanh(0.999).
// So the whole pipeline is 3 GEMMs with per-row clip-norm/tanh between them,
// plus a 16-dim mobius epilogue (general in bc; collapses for bc=0).

typedef __bf16 bfrag __attribute__((ext_vector_type(8)));   // MFMA A/B operand (4 VGPR)
typedef __bf16 bf4   __attribute__((ext_vector_type(4)));
typedef float  ffrag __attribute__((ext_vector_type(4)));   // MFMA C/D (4 VGPR)

#define ACLIP 3.8002012f   // atanh(0.999)

__device__ __forceinline__ float tanh_fast(float x) {
  float ax = fabsf(x);
  float e = __expf(fminf(2.0f * ax, 30.0f));
  float t = 1.0f - __fdividef(2.0f, e + 1.0f);
  return copysignf(t, x);
}
__device__ __forceinline__ float rsum16(float v) {
  v += __shfl_xor(v, 1);
  v += __shfl_xor(v, 2);
  v += __shfl_xor(v, 4);
  v += __shfl_xor(v, 8);
  return v;
}

// async 16B global -> LDS (DMA, no VGPR round-trip)
__device__ __forceinline__ void gl_lds16(const __bf16* g, __bf16* l) {
  __builtin_amdgcn_global_load_lds(
      (const __attribute__((address_space(1))) void*)g,
      (__attribute__((address_space(3))) void*)l, 16, 0, 0);
}
// stage one 16 KiB k-slice (1024 slots x 16B) with 256 threads: 4 issues/thread
__device__ __forceinline__ void stage_slice(const __bf16* src, __bf16* dst, int tid) {
  #pragma unroll
  for (int i = 0; i < 4; ++i)
    gl_lds16(src + (i * 256 + tid) * 8, dst + (i * 256 + tid) * 8);
}

// ---------------------------------------------------------------------------
// prep: reorder W1/W2/Wc (f32 row-major [out][in]) into bf16 MFMA b-fragment
// order in ws:  slot(stage, ks, nt, lane) holds W[nt*16 + (lane&15)]
//                                              [ks*32 + (lane>>4)*8 .. +7]
// W1 at elem 0, W2 at 65536, Wc at 131072
// ---------------------------------------------------------------------------
__global__ void prep_kernel(const float* __restrict__ W1, const float* __restrict__ W2,
                            const float* __restrict__ Wc, __bf16* __restrict__ wsb) {
  int g = blockIdx.x * 256 + threadIdx.x;   // 0..16895
  const float* src; int s, base;
  if (g < 8192)        { src = W1; s = g;         base = 0;      }
  else if (g < 16384)  { src = W2; s = g - 8192;  base = 65536;  }
  else                 { src = Wc; s = g - 16384; base = 131072; }
  int l = s & 63, t = s >> 6;
  int nt, ks;
  if (g < 16384) { nt = t & 15; ks = t >> 4; }
  else           { nt = 0;      ks = t;      }
  int row  = nt * 16 + (l & 15);
  int col0 = ks * 32 + (l >> 4) * 8;
  bfrag v;
  #pragma unroll
  for (int j = 0; j < 8; ++j) v[j] = (__bf16)src[row * 256 + col0 + j];
  *(bfrag*)(wsb + base + s * 8) = v;
}

// ---------------------------------------------------------------------------
// fused main kernel: 64 rows/block, 4 waves, each wave owns a 64-col slice.
// A-tile LDS XOR-swizzled (conflict-free b128); B double-buffered via
// global_load_lds with 1 barrier per k-step; all shfl reductions batched.
// ---------------------------------------------------------------------------
__global__ __launch_bounds__(256) void fused_kernel(
    const float* __restrict__ x, const float* __restrict__ b1,
    const float* __restrict__ b2, const float* __restrict__ bc,
    const __bf16* __restrict__ wsb, float* __restrict__ out) {
  __shared__ __bf16 At[64 * 256];     // 32 KiB swizzled, 512 B/row
  __shared__ __bf16 Bt[2][1024 * 8];  // 2 x 16 KiB double-buffered k-slice
  __shared__ float nrmA[64][4];
  __shared__ float nrmB[64][4];

  const int tid  = threadIdx.x;
  const int w    = tid >> 6;
  const int lane = tid & 63;
  const int lrow = lane & 15;
  const int lgrp = lane >> 4;
  const int swzA = (lrow & 7) << 4;
  const long long rowg = (long long)blockIdx.x * 64;

  // prefetch W1 k-slice 0 while we chew on x
  stage_slice(wsb, Bt[0], tid);

  // ---- stage 0: load x (16 rows/wave), clip_norm(x, A), write bf16 A ----
  // loads batched ahead of reductions; reductions batched level-by-level.
  #pragma unroll
  for (int half = 0; half < 2; ++half) {
    float4 v[8]; float ss[8];
    #pragma unroll
    for (int rr = 0; rr < 8; ++rr) {
      int row = w * 16 + half * 8 + rr;
      v[rr] = *(const float4*)(x + (rowg + row) * 256 + lane * 4);
    }
    #pragma unroll
    for (int rr = 0; rr < 8; ++rr)
      ss[rr] = v[rr].x * v[rr].x + v[rr].y * v[rr].y + v[rr].z * v[rr].z + v[rr].w * v[rr].w;
    #pragma unroll
    for (int m = 1; m < 64; m <<= 1)
      #pragma unroll
      for (int rr = 0; rr < 8; ++rr) ss[rr] += __shfl_xor(ss[rr], m);
    #pragma unroll
    for (int rr = 0; rr < 8; ++rr) {
      int row = w * 16 + half * 8 + rr;
      float f = fminf(1.0f, ACLIP * rsqrtf(fmaxf(ss[rr], 1e-30f)));
      bf4 z;
      z[0] = (__bf16)(v[rr].x * f); z[1] = (__bf16)(v[rr].y * f);
      z[2] = (__bf16)(v[rr].z * f); z[3] = (__bf16)(v[rr].w * f);
      *(bf4*)((char*)At + row * 512 + ((lane * 8) ^ ((row & 7) << 4))) = z;
    }
  }

  ffrag acc[4][4];

  #pragma unroll
  for (int st = 0; st < 2; ++st) {
    const __bf16* wb   = wsb + (st ? 65536 : 0);
    const float*  bias = st ? b2 : b1;
    #pragma unroll
    for (int rt = 0; rt < 4; ++rt)
      #pragma unroll
      for (int ct = 0; ct < 4; ++ct)
        acc[rt][ct] = (ffrag){0.f, 0.f, 0.f, 0.f};

    __syncthreads();   // At visible; Bt[0] staged (syncthreads drains vmcnt)

    #pragma unroll
    for (int ks = 0; ks < 8; ++ks) {
      const __bf16* curB = Bt[ks & 1];
      __bf16*       nxtB = Bt[(ks + 1) & 1];
      if (ks < 7)        stage_slice(wb + (ks + 1) * 8192, nxtB, tid);
      else if (st == 0)  stage_slice(wsb + 65536, nxtB, tid);  // W2 slice 0
      bfrag areg[4], breg[4];
      #pragma unroll
      for (int rt = 0; rt < 4; ++rt)
        areg[rt] = *(const bfrag*)((const char*)At + (rt * 16 + lrow) * 512 +
                                   ((ks * 64 + lgrp * 16) ^ swzA));
      #pragma unroll
      for (int ct = 0; ct < 4; ++ct)
        breg[ct] = *(const bfrag*)(curB + ((w * 4 + ct) * 64 + lane) * 8);
      #pragma unroll
      for (int rt = 0; rt < 4; ++rt)
        #pragma unroll
        for (int ct = 0; ct < 4; ++ct)
          acc[rt][ct] = __builtin_amdgcn_mfma_f32_16x16x32_bf16(
              areg[rt], breg[ct], acc[rt][ct], 0, 0, 0);
      __syncthreads();  // drains next-slice DMA; protects buffer reuse
    }

    // ---- elementwise epilogue: +bias, clip_norm, tanh, clip_norm ----
    float bb[4];
    #pragma unroll
    for (int ct = 0; ct < 4; ++ct) bb[ct] = bias[w * 64 + ct * 16 + lrow];
    #pragma unroll
    for (int ct = 0; ct < 4; ++ct)
      #pragma unroll
      for (int rt = 0; rt < 4; ++rt)
        #pragma unroll
        for (int r = 0; r < 4; ++r) acc[rt][ct][r] += bb[ct];

    float s[16];
    #pragma unroll
    for (int rt = 0; rt < 4; ++rt)
      #pragma unroll
      for (int r = 0; r < 4; ++r) {
        float t = 0.f;
        #pragma unroll
        for (int ct = 0; ct < 4; ++ct) t += acc[rt][ct][r] * acc[rt][ct][r];
        s[rt * 4 + r] = t;
      }
    #pragma unroll
    for (int m = 1; m < 16; m <<= 1)
      #pragma unroll
      for (int i = 0; i < 16; ++i) s[i] += __shfl_xor(s[i], m);
    if (lrow == 0) {
      #pragma unroll
      for (int rt = 0; rt < 4; ++rt)
        #pragma unroll
        for (int r = 0; r < 4; ++r)
          nrmA[rt * 16 + lgrp * 4 + r][w] = s[rt * 4 + r];
    }
    __syncthreads();

    float s2[16];
    #pragma unroll
    for (int rt = 0; rt < 4; ++rt)
      #pragma unroll
      for (int r = 0; r < 4; ++r) {
        const float4 nv = *(const float4*)&nrmA[rt * 16 + lgrp * 4 + r][0];
        float tot = nv.x + nv.y + nv.z + nv.w;
        float f = fminf(1.0f, ACLIP * rsqrtf(fmaxf(tot, 1e-30f)));
        float t = 0.f;
        #pragma unroll
        for (int ct = 0; ct < 4; ++ct) {
          float z = tanh_fast(acc[rt][ct][r] * f);
          acc[rt][ct][r] = z;
          t += z * z;
        }
        s2[rt * 4 + r] = t;
      }
    #pragma unroll
    for (int m = 1; m < 16; m <<= 1)
      #pragma unroll
      for (int i = 0; i < 16; ++i) s2[i] += __shfl_xor(s2[i], m);
    if (lrow == 0) {
      #pragma unroll
      for (int rt = 0; rt < 4; ++rt)
        #pragma unroll
        for (int r = 0; r < 4; ++r)
          nrmB[rt * 16 + lgrp * 4 + r][w] = s2[rt * 4 + r];
    }
    __syncthreads();

    #pragma unroll
    for (int rt = 0; rt < 4; ++rt)
      #pragma unroll
      for (int r = 0; r < 4; ++r) {
        const float4 nv = *(const float4*)&nrmB[rt * 16 + lgrp * 4 + r][0];
        float tot = nv.x + nv.y + nv.z + nv.w;
        float f2 = fminf(1.0f, ACLIP * rsqrtf(fmaxf(tot, 1e-30f)));
        int row = rt * 16 + lgrp * 4 + r;
        #pragma unroll
        for (int ct = 0; ct < 4; ++ct) {
          float y = acc[rt][ct][r] * f2;
          int cb = (w * 64 + ct * 16 + lrow) * 2;
          *(__bf16*)((char*)At + row * 512 + (cb ^ ((row & 7) << 4))) = (__bf16)y;
        }
      }
  }
  __syncthreads();   // y2 visible for classifier a-reads

  // ---- classifier: m = y2 @ Wc^T (16 cols), then mobius epilogue ----
  float bcv = bc[lrow];
  float pb2 = rsum16(bcv * bcv);
  float nb  = sqrtf(fmaxf(pb2, 1e-30f));
  float tnb = tanh_fast(nb);
  float pratio = (nb < 1e-4f) ? 1.0f : __fdividef(fminf(tnb, 0.999f), nb);
  float pj = bcv * pratio;            // hyp_bias component (class lrow)
  float p2 = rsum16(pj * pj);

  ffrag c2 = (ffrag){0.f, 0.f, 0.f, 0.f};
  #pragma unroll
  for (int ks = 0; ks < 8; ++ks) {
    bfrag a = *(const bfrag*)((const char*)At + (w * 16 + lrow) * 512 +
                              ((ks * 64 + lgrp * 16) ^ swzA));
    bfrag b = *(const bfrag*)(wsb + 131072 + (ks * 64 + lane) * 8);
    c2 = __builtin_amdgcn_mfma_f32_16x16x32_bf16(a, b, c2, 0, 0, 0);
  }

  // batched mobius epilogue over the 4 accumulator rows
  float m[4], g2[4], xj[4], x2[4], xy[4], r2j[4], n2s[4];
  #pragma unroll
  for (int r = 0; r < 4; ++r) { m[r] = c2[r]; g2[r] = m[r] * m[r]; }
  #pragma unroll
  for (int mm = 1; mm < 16; mm <<= 1)
    #pragma unroll
    for (int r = 0; r < 4; ++r) g2[r] += __shfl_xor(g2[r], mm);
  #pragma unroll
  for (int r = 0; r < 4; ++r) {
    float gn = sqrtf(fmaxf(g2[r], 1e-30f));
    float tg = tanh_fast(gn);
    float rn = fminf(tg, 0.999f);
    float ratio = (gn < 1e-4f) ? 1.0f : __fdividef(rn, gn);
    xj[r] = m[r] * ratio;
    x2[r] = ratio * ratio * g2[r];
    xy[r] = xj[r] * pj;
  }
  #pragma unroll
  for (int mm = 1; mm < 16; mm <<= 1)
    #pragma unroll
    for (int r = 0; r < 4; ++r) xy[r] += __shfl_xor(xy[r], mm);
  #pragma unroll
  for (int r = 0; r < 4; ++r) {
    float na = 1.f + 2.f * xy[r] + p2;
    float de = fmaxf(1.f + 2.f * xy[r] + x2[r] * p2, 1e-15f);
    r2j[r] = (na * xj[r] + (1.f - x2[r]) * pj) / de;
    n2s[r] = r2j[r] * r2j[r];
  }
  #pragma unroll
  for (int mm = 1; mm < 16; mm <<= 1)
    #pragma unroll
    for (int r = 0; r < 4; ++r) n2s[r] += __shfl_xor(n2s[r], mm);
  #pragma unroll
  for (int r = 0; r < 4; ++r) {
    float n2 = sqrtf(fmaxf(n2s[r], 1e-30f));
    float pscl = (n2 > 0.999f) ? (0.999f / n2) : 1.0f;
    float v = r2j[r] * pscl;
    float n3 = fminf(n2, 0.999f);
    float lfac = (n3 < 1e-4f)
                     ? 1.0f
                     : __fdividef(0.5f * __logf((1.f + n3) / (1.f - n3)), n3);
    float lg = v * lfac;
    float sp = (lg > 20.f) ? lg : log1pf(__expf(lg));
    long long row = rowg + w * 16 + lgrp * 4 + r;
    out[row * 16 + lrow] = sp;
  }
}

extern "C" void kernel_launch(void* const* d_in, const int* in_sizes, int n_in,
                              void* d_out, int out_size, void* d_ws, size_t ws_size,
                              hipStream_t stream) {
  (void)in_sizes; (void)n_in; (void)out_size; (void)ws_size;
  const float* x  = (const float*)d_in[0];
  const float* W1 = (const float*)d_in[1];
  const float* b1 = (const float*)d_in[2];
  const float* W2 = (const float*)d_in[3];
  const float* b2 = (const float*)d_in[4];
  const float* Wc = (const float*)d_in[5];
  const float* bc = (const float*)d_in[6];
  __bf16* wsb = (__bf16*)d_ws;          // needs 270336 B

  prep_kernel<<<66, 256, 0, stream>>>(W1, W2, Wc, wsb);
  fused_kernel<<<4096, 256, 0, stream>>>(x, b1, b2, bc, wsb, (float*)d_out);
}

// Round 3
// 206.594 us; speedup vs baseline: 2.7300x; 2.0731x over previous
//
#include <hip/hip_runtime.h>
#include <hip/hip_bf16.h>

// Fused hyperbolic MLP forward.
// Identity: logmap0(proj(expmap0(u))) == clip_norm(u, A), A = atanh(0.999).
// Classifier: res = min(tanh(f2*||v||),0.999)*unit(v), v = z2@Wc^T (scale-exact,
// verified algebraically: the expmap/logmap norms cancel).
// Layout: SWAPPED mfma operands -> D[feature][batch]; lane holds 16 features of
// 4 batch rows => per-row reductions are 16 local FMA + 2 shfls (x^16,x^32).

typedef __bf16 bfrag __attribute__((ext_vector_type(8)));   // MFMA A/B (4 VGPR)
typedef __bf16 bf4   __attribute__((ext_vector_type(4)));
typedef float  ffrag __attribute__((ext_vector_type(4)));   // MFMA C/D

#define ACLIP 3.8002012f   // atanh(0.999)

__device__ __forceinline__ float tanh_fast(float x) {
  float ax = fabsf(x);
  float e  = __expf(2.0f * ax);
  float t  = 1.0f - __fdividef(2.0f, e + 1.0f);
  return copysignf(t, x);
}

__device__ __forceinline__ void gl_lds16(const __bf16* g, __bf16* l) {
  __builtin_amdgcn_global_load_lds(
      (const __attribute__((address_space(1))) void*)g,
      (__attribute__((address_space(3))) void*)l, 16, 0, 0);
}
__device__ __forceinline__ void stage_slice(const __bf16* src, __bf16* dst, int tid) {
#pragma unroll
  for (int i = 0; i < 4; ++i)
    gl_lds16(src + (i * 256 + tid) * 8, dst + (i * 256 + tid) * 8);
}
__device__ __forceinline__ void stage_wc(const __bf16* src, __bf16* dst, int tid) {
#pragma unroll
  for (int i = 0; i < 2; ++i)
    gl_lds16(src + (i * 256 + tid) * 8, dst + (i * 256 + tid) * 8);
}

// ---------------------------------------------------------------------------
// prep: reorder W1/W2/Wc (f32 [out][in]) into bf16 MFMA fragment order:
// slot(ks, nt, lane) holds W[nt*16 + (lane&15)][ks*32 + (lane>>4)*8 .. +7]
// W1 slices 0-7 (elem 0), W2 slices 8-15 (elem 65536), Wc at 131072.
// ---------------------------------------------------------------------------
__global__ void prep_kernel(const float* __restrict__ W1, const float* __restrict__ W2,
                            const float* __restrict__ Wc, __bf16* __restrict__ wsb) {
  int g = blockIdx.x * 256 + threadIdx.x;   // 0..16895
  const float* src; int s, base;
  if (g < 8192)        { src = W1; s = g;         base = 0;      }
  else if (g < 16384)  { src = W2; s = g - 8192;  base = 65536;  }
  else                 { src = Wc; s = g - 16384; base = 131072; }
  int l = s & 63, t = s >> 6;
  int nt, ks;
  if (g < 16384) { nt = t & 15; ks = t >> 4; }
  else           { nt = 0;      ks = t;      }
  int row  = nt * 16 + (l & 15);
  int col0 = ks * 32 + (l >> 4) * 8;
  bfrag v;
#pragma unroll
  for (int j = 0; j < 8; ++j) v[j] = (__bf16)src[row * 256 + col0 + j];
  *(bfrag*)(wsb + base + s * 8) = v;
}

// ---------------------------------------------------------------------------
// fused main: 64 rows/block, 4 waves; wave w owns features w*64..w*64+63 for
// ALL 64 batch rows (acc[ft][bt], feature = w*64+ft*16+lgrp*4+r, batch =
// bt*16+lrow). A-tile (X, bf16 raw) XOR-swizzled in LDS; W double-buffered
// via global_load_lds; input clip-norm factor folded into stage-1 epilogue.
// ---------------------------------------------------------------------------
__global__ __launch_bounds__(256, 2) void fused_kernel(
    const float* __restrict__ x, const float* __restrict__ b1,
    const float* __restrict__ b2, const float* __restrict__ bc,
    const __bf16* __restrict__ wsb, float* __restrict__ out) {
  __shared__ __align__(16) __bf16 At[64 * 256];   // 32 KB, 512 B/row, swizzled
  __shared__ __align__(16) __bf16 Bt[2][8192];    // 2 x 16 KB W k-slices
  __shared__ float partX[64][4];
  __shared__ float pE1[64][4];
  __shared__ float pE2[64][4];

  const int tid  = threadIdx.x;
  const int w    = tid >> 6;
  const int lane = tid & 63;
  const int lrow = lane & 15;
  const int lgrp = lane >> 4;
  const int swz  = (lrow & 7) << 4;
  const long long rowg = (long long)blockIdx.x * 64;

  // ---- prologue: x loads (HBM) + first W slice (L2), raw bf16 At, partial norms
  float4 xv[16];
#pragma unroll
  for (int rr = 0; rr < 16; ++rr)
    xv[rr] = *(const float4*)(x + (rowg + w * 16 + rr) * 256 + lane * 4);
  stage_slice(wsb, Bt[0], tid);

  float ss[16];
#pragma unroll
  for (int rr = 0; rr < 16; ++rr) {
    int row = w * 16 + rr;
    bf4 z;
    z[0] = (__bf16)xv[rr].x; z[1] = (__bf16)xv[rr].y;
    z[2] = (__bf16)xv[rr].z; z[3] = (__bf16)xv[rr].w;
    *(bf4*)((char*)At + row * 512 + ((lane * 8) ^ ((row & 7) << 4))) = z;
    ss[rr] = xv[rr].x * xv[rr].x + xv[rr].y * xv[rr].y +
             xv[rr].z * xv[rr].z + xv[rr].w * xv[rr].w;
  }
#pragma unroll
  for (int m = 1; m <= 8; m <<= 1)
#pragma unroll
    for (int rr = 0; rr < 16; ++rr) ss[rr] += __shfl_xor(ss[rr], m);
  if (lrow == 0) {   // lanes 0,16,32,48: group-partials for the wave's 16 rows
#pragma unroll
    for (int rr = 0; rr < 16; ++rr) partX[w * 16 + rr][lgrp] = ss[rr];
  }
  __syncthreads();   // At + partX visible; Bt[0] DMA drained

  ffrag acc[4][4];   // [ft][bt]

#pragma unroll
  for (int st = 0; st < 2; ++st) {
#pragma unroll
    for (int ft = 0; ft < 4; ++ft)
#pragma unroll
      for (int bt = 0; bt < 4; ++bt) acc[ft][bt] = (ffrag){0.f, 0.f, 0.f, 0.f};

#pragma unroll
    for (int j = 0; j < 8; ++j) {
      const int t = st * 8 + j;
      if (t < 15) stage_slice(wsb + (t + 1) * 8192, Bt[(t + 1) & 1], tid);
      else        stage_wc(wsb + 131072, Bt[0], tid);   // Wc into Bt[0]
      const __bf16* cb = Bt[t & 1];
      bfrag wf[4], xf[4];
#pragma unroll
      for (int ft = 0; ft < 4; ++ft)
        wf[ft] = *(const bfrag*)(cb + ((w * 4 + ft) * 64 + lane) * 8);
#pragma unroll
      for (int bt = 0; bt < 4; ++bt)
        xf[bt] = *(const bfrag*)((const char*)At + (bt * 16 + lrow) * 512 +
                                 ((j * 64 + lgrp * 16) ^ swz));
#pragma unroll
      for (int ft = 0; ft < 4; ++ft)
#pragma unroll
        for (int bt = 0; bt < 4; ++bt)
          acc[ft][bt] = __builtin_amdgcn_mfma_f32_16x16x32_bf16(
              wf[ft], xf[bt], acc[ft][bt], 0, 0, 0);
      __syncthreads();   // drains next-slice DMA; protects buffer reuse
    }

    // ---- epilogue: u = fr*acc + bias; clip_norm; tanh; clip_norm; y -> At ----
    const float* bias = st ? b2 : b1;
    float bb[4][4];
#pragma unroll
    for (int ft = 0; ft < 4; ++ft)
#pragma unroll
      for (int r = 0; r < 4; ++r) bb[ft][r] = bias[w * 64 + ft * 16 + lgrp * 4 + r];

    float f0[4];
    if (st == 0) {
#pragma unroll
      for (int bt = 0; bt < 4; ++bt) {
        const float4 p = *(const float4*)partX[bt * 16 + lrow];
        float s = p.x + p.y + p.z + p.w;
        f0[bt] = fminf(1.0f, ACLIP * rsqrtf(fmaxf(s, 1e-30f)));
      }
    } else {
#pragma unroll
      for (int bt = 0; bt < 4; ++bt) f0[bt] = 1.0f;
    }

    float s1[4] = {0.f, 0.f, 0.f, 0.f};
#pragma unroll
    for (int ft = 0; ft < 4; ++ft)
#pragma unroll
      for (int bt = 0; bt < 4; ++bt)
#pragma unroll
        for (int r = 0; r < 4; ++r) {
          float u = acc[ft][bt][r] * f0[bt] + bb[ft][r];
          acc[ft][bt][r] = u;
          s1[bt] += u * u;
        }
#pragma unroll
    for (int bt = 0; bt < 4; ++bt) {
      s1[bt] += __shfl_xor(s1[bt], 16);
      s1[bt] += __shfl_xor(s1[bt], 32);
    }
    if (lgrp == 0) {
#pragma unroll
      for (int bt = 0; bt < 4; ++bt) pE1[bt * 16 + lrow][w] = s1[bt];
    }
    __syncthreads();

    float f1[4];
#pragma unroll
    for (int bt = 0; bt < 4; ++bt) {
      const float4 p = *(const float4*)pE1[bt * 16 + lrow];
      float s = p.x + p.y + p.z + p.w;
      f1[bt] = fminf(1.0f, ACLIP * rsqrtf(fmaxf(s, 1e-30f)));
    }
    float s2[4] = {0.f, 0.f, 0.f, 0.f};
#pragma unroll
    for (int ft = 0; ft < 4; ++ft)
#pragma unroll
      for (int bt = 0; bt < 4; ++bt)
#pragma unroll
        for (int r = 0; r < 4; ++r) {
          float zz = tanh_fast(acc[ft][bt][r] * f1[bt]);
          acc[ft][bt][r] = zz;
          s2[bt] += zz * zz;
        }
#pragma unroll
    for (int bt = 0; bt < 4; ++bt) {
      s2[bt] += __shfl_xor(s2[bt], 16);
      s2[bt] += __shfl_xor(s2[bt], 32);
    }
    if (lgrp == 0) {
#pragma unroll
      for (int bt = 0; bt < 4; ++bt) pE2[bt * 16 + lrow][w] = s2[bt];
    }
    __syncthreads();

#pragma unroll
    for (int bt = 0; bt < 4; ++bt) {
      const float4 p = *(const float4*)pE2[bt * 16 + lrow];
      float s = p.x + p.y + p.z + p.w;
      float f2 = fminf(1.0f, ACLIP * rsqrtf(fmaxf(s, 1e-30f)));
      int row = bt * 16 + lrow;
#pragma unroll
      for (int ft = 0; ft < 4; ++ft) {
        bf4 yv;
#pragma unroll
        for (int r = 0; r < 4; ++r) yv[r] = (__bf16)(acc[ft][bt][r] * f2);
        *(bf4*)((char*)At + row * 512 +
                (((w * 64 + ft * 16 + lgrp * 4) * 2) ^ ((row & 7) << 4))) = yv;
      }
    }
    __syncthreads();   // y visible for next stage / classifier
  }

  // ---- classifier: v = y2 @ Wc^T (16 classes), mobius epilogue ----
  // lane: batch = w*16+lrow, classes lgrp*4+r (reduce over lgrp: 2 shfls)
  float bcv[4];
#pragma unroll
  for (int r = 0; r < 4; ++r) bcv[r] = bc[lgrp * 4 + r];
  float pp = bcv[0]*bcv[0] + bcv[1]*bcv[1] + bcv[2]*bcv[2] + bcv[3]*bcv[3];
  pp += __shfl_xor(pp, 16); pp += __shfl_xor(pp, 32);
  float nb = sqrtf(fmaxf(pp, 1e-30f));
  float tnb = tanh_fast(nb);
  float pratio = (nb < 1e-4f) ? 1.0f : __fdividef(fminf(tnb, 0.999f), nb);
  float pj[4];
#pragma unroll
  for (int r = 0; r < 4; ++r) pj[r] = bcv[r] * pratio;
  float p2 = pratio * pratio * pp;

  ffrag c2 = (ffrag){0.f, 0.f, 0.f, 0.f};
#pragma unroll
  for (int ks = 0; ks < 8; ++ks) {
    bfrag a = *(const bfrag*)(Bt[0] + (ks * 64 + lane) * 8);
    bfrag b = *(const bfrag*)((const char*)At + (w * 16 + lrow) * 512 +
                              ((ks * 64 + lgrp * 16) ^ swz));
    c2 = __builtin_amdgcn_mfma_f32_16x16x32_bf16(a, b, c2, 0, 0, 0);
  }
  float g2 = c2[0]*c2[0] + c2[1]*c2[1] + c2[2]*c2[2] + c2[3]*c2[3];
  g2 += __shfl_xor(g2, 16); g2 += __shfl_xor(g2, 32);
  float gn = sqrtf(fmaxf(g2, 1e-30f));
  float tg = tanh_fast(gn);
  float rn = fminf(tg, 0.999f);
  float ratio = (gn < 1e-4f) ? 1.0f : __fdividef(rn, gn);
  float x2 = ratio * ratio * g2;
  float xj[4], r2j[4];
  float xy = 0.f;
#pragma unroll
  for (int r = 0; r < 4; ++r) { xj[r] = c2[r] * ratio; xy += xj[r] * pj[r]; }
  xy += __shfl_xor(xy, 16); xy += __shfl_xor(xy, 32);
  float na = 1.f + 2.f * xy + p2;
  float de = fmaxf(1.f + 2.f * xy + x2 * p2, 1e-15f);
  float rde = __fdividef(1.0f, de);
  float n2s = 0.f;
#pragma unroll
  for (int r = 0; r < 4; ++r) {
    r2j[r] = (na * xj[r] + (1.f - x2) * pj[r]) * rde;
    n2s += r2j[r] * r2j[r];
  }
  n2s += __shfl_xor(n2s, 16); n2s += __shfl_xor(n2s, 32);
  float n2 = sqrtf(fmaxf(n2s, 1e-30f));
  float pscl = (n2 > 0.999f) ? (0.999f / n2) : 1.0f;
  float n3 = fminf(n2, 0.999f);
  float lfac = (n3 < 1e-4f)
                   ? 1.0f
                   : __fdividef(0.5f * __logf((1.f + n3) / (1.f - n3)), n3);
  float* oT = (float*)Bt[1];   // reuse as [64][17] f32 staging (4.4 KB)
#pragma unroll
  for (int r = 0; r < 4; ++r) {
    float lg = r2j[r] * pscl * lfac;
    float sp = (lg > 20.f) ? lg : log1pf(__expf(lg));
    oT[(w * 16 + lrow) * 17 + lgrp * 4 + r] = sp;
  }
  __syncthreads();
  {
    int row = tid >> 2, c = (tid & 3) * 4;
    float4 o;
    o.x = oT[row * 17 + c];     o.y = oT[row * 17 + c + 1];
    o.z = oT[row * 17 + c + 2]; o.w = oT[row * 17 + c + 3];
    *(float4*)(out + (rowg + row) * 16 + c) = o;
  }
}

extern "C" void kernel_launch(void* const* d_in, const int* in_sizes, int n_in,
                              void* d_out, int out_size, void* d_ws, size_t ws_size,
                              hipStream_t stream) {
  (void)in_sizes; (void)n_in; (void)out_size; (void)ws_size;
  const float* x  = (const float*)d_in[0];
  const float* W1 = (const float*)d_in[1];
  const float* b1 = (const float*)d_in[2];
  const float* W2 = (const float*)d_in[3];
  const float* b2 = (const float*)d_in[4];
  const float* Wc = (const float*)d_in[5];
  const float* bc = (const float*)d_in[6];
  __bf16* wsb = (__bf16*)d_ws;          // needs 270336 B

  prep_kernel<<<66, 256, 0, stream>>>(W1, W2, Wc, wsb);
  fused_kernel<<<4096, 256, 0, stream>>>(x, b1, b2, bc, wsb, (float*)d_out);
}